// Round 4
// baseline (225.984 us; speedup 1.0000x reference)
//
#include <hip/hip_runtime.h>

// x [B,C,H,W] fp32, guide [B,1,H,W] fp32.
// out[b,c,h,t] = max_{j<=t} x[b,c,h,j]*guide[b,0,h,j]  (cummax along W)
#define PB 8
#define PC 256
#define PH 128
#define PW 128
#define TOTAL_ROWS (PB * PC * PH)   // 262144
#define QROWS (TOTAL_ROWS / 4)      // 65536 rows per slice

// Native clang vector type — __builtin_nontemporal_* requires this.
typedef float vfloat4 __attribute__((ext_vector_type(4)));

// One 32-lane segment per row (lane owns a float4). Each thread processes
// FOUR independent rows (r + i*QROWS) — 128 B of streaming loads in flight
// per thread before any dependent math. x/out are non-temporal (streaming);
// guide cached (256x reuse per line).
__global__ __launch_bounds__(256) void i5pool_cummax_kernel(
    const float* __restrict__ x,
    const float* __restrict__ guide,
    float* __restrict__ out)
{
    const int tid   = blockIdx.x * blockDim.x + threadIdx.x;
    const int sub   = tid & 31;        // quad index within row
    const int rbase = tid >> 5;        // 0..QROWS-1

    int rows[4];
    #pragma unroll
    for (int i = 0; i < 4; ++i) rows[i] = rbase + i * QROWS;

    // Issue all loads up front (4 independent x streams + 4 guide reads).
    vfloat4 xv[4], gv[4];
    #pragma unroll
    for (int i = 0; i < 4; ++i) {
        const int r = rows[i];
        const int h = r & (PH - 1);
        const int b = r >> 15;         // r / (PC*PH)
        xv[i] = __builtin_nontemporal_load((const vfloat4*)(x + (size_t)r * PW) + sub);
        gv[i] = *((const vfloat4*)(guide + ((size_t)b * PH + h) * PW) + sub);
    }

    // Local 4-element inclusive max-scans (independent across rows).
    float s[4][4];
    #pragma unroll
    for (int i = 0; i < 4; ++i) {
        s[i][0] = xv[i].x * gv[i].x;
        s[i][1] = fmaxf(s[i][0], xv[i].y * gv[i].y);
        s[i][2] = fmaxf(s[i][1], xv[i].z * gv[i].z);
        s[i][3] = fmaxf(s[i][2], xv[i].w * gv[i].w);
    }

    // Interleaved 32-lane inclusive max-scans of lane totals (4-way ILP).
    float inc[4];
    #pragma unroll
    for (int i = 0; i < 4; ++i) inc[i] = s[i][3];
    #pragma unroll
    for (int d = 1; d < 32; d <<= 1) {
        float t[4];
        #pragma unroll
        for (int i = 0; i < 4; ++i) t[i] = __shfl_up(inc[i], d, 32);
        if (sub >= d) {
            #pragma unroll
            for (int i = 0; i < 4; ++i) inc[i] = fmaxf(inc[i], t[i]);
        }
    }

    #pragma unroll
    for (int i = 0; i < 4; ++i) {
        float pre = __shfl_up(inc[i], 1, 32);
        if (sub > 0) {
            #pragma unroll
            for (int j = 0; j < 4; ++j) s[i][j] = fmaxf(s[i][j], pre);
        }
        vfloat4 ov = {s[i][0], s[i][1], s[i][2], s[i][3]};
        __builtin_nontemporal_store(ov, (vfloat4*)(out + (size_t)rows[i] * PW) + sub);
    }
}

extern "C" void kernel_launch(void* const* d_in, const int* in_sizes, int n_in,
                              void* d_out, int out_size, void* d_ws, size_t ws_size,
                              hipStream_t stream) {
    const float* x     = (const float*)d_in[0];
    const float* guide = (const float*)d_in[1];
    float* out = (float*)d_out;

    // QROWS rows per slice, 32 lanes per row -> 2,097,152 threads
    const int total_threads = QROWS * (PW / 4);
    const int block = 256;
    const int grid = total_threads / block;  // 8192

    i5pool_cummax_kernel<<<grid, block, 0, stream>>>(x, guide, out);
}